// Round 3
// baseline (479.624 us; speedup 1.0000x reference)
//
#include <hip/hip_runtime.h>
#include <hip/hip_bf16.h>
#include <stdint.h>
#include <stddef.h>

// Problem constants
#define Bn  2
#define Tn  2048
#define Cn  2048
#define Hn  16
#define HDn 128

// may_alias vector types for memory access (TBAA-safe); plain short8 for MFMA args
typedef short short8   __attribute__((ext_vector_type(8)));
typedef short short8_a __attribute__((ext_vector_type(8), may_alias));
typedef unsigned int u32x4_a __attribute__((ext_vector_type(4), may_alias));
typedef unsigned short u16x4_a __attribute__((ext_vector_type(4), may_alias));
typedef unsigned short u16x8_a __attribute__((ext_vector_type(8), may_alias));
typedef float f32x4 __attribute__((ext_vector_type(4)));

// address-space-qualified void for global_load_lds
typedef __attribute__((address_space(1))) const void av1_t;
typedef __attribute__((address_space(3))) void av3_t;

__device__ inline unsigned short f2b(float f) {
    union { float f; unsigned u; } v; v.f = f;
    unsigned r = v.u + 0x7fffu + ((v.u >> 16) & 1u);   // RNE
    return (unsigned short)(r >> 16);
}
__device__ inline u16x4_a cvt4_f32_bf16(u32x4_a v) {
    u16x4_a h;
#pragma unroll
    for (int e = 0; e < 4; e++) {
        unsigned u = v[e];
        unsigned r = u + 0x7fffu + ((u >> 16) & 1u);
        h[e] = (unsigned short)(r >> 16);
    }
    return h;
}

// ---------------- fp32 -> bf16 bulk convert (memory-bound) ----------------
__global__ __launch_bounds__(256)
void cvt_kernel(const float* __restrict__ src, unsigned short* __restrict__ dst, int n)
{
    const int i = (blockIdx.x * 256 + threadIdx.x) * 8;
    if (i >= n) return;
    u32x4_a a = *(const u32x4_a*)((const unsigned*)src + i);
    u32x4_a b = *(const u32x4_a*)((const unsigned*)src + i + 4);
    u16x8_a o;
    u16x4_a ha = cvt4_f32_bf16(a), hb = cvt4_f32_bf16(b);
#pragma unroll
    for (int e = 0; e < 4; e++) { o[e] = ha[e]; o[e + 4] = hb[e]; }
    *(u16x8_a*)(dst + i) = o;
}

// ---------------- pure-bf16 GEMM, m97-style global_load_lds staging ----------------
// Proven ~50 us for the proj GEMM at grid(32,16)x256thr (512 blocks, 2 blk/CU).
template<int OUT_F32, int HAS_BIAS>
__global__ __launch_bounds__(256)
void gemm_bb_kernel(const unsigned short* __restrict__ A,
                    const unsigned short* __restrict__ Bm,
                    const float* __restrict__ bias, void* __restrict__ Cv,
                    int M, int N, int K)
{
    __shared__ __align__(16) unsigned short As[128 * 32];
    __shared__ __align__(16) unsigned short Bs[128 * 32];

    const int tid  = threadIdx.x;
    const int lane = tid & 63;
    const int wave = tid >> 6;
    const int quad = lane >> 4;
    const int l15  = lane & 15;
    const int tm = blockIdx.x * 128;
    const int tn = blockIdx.y * 128;
    const int wr = (wave >> 1) * 64;
    const int wc = (wave & 1) * 64;

    const int srow = lane >> 2;
    const int scol = (lane & 3) * 8;

    f32x4 acc[4][4];
#pragma unroll
    for (int i = 0; i < 4; i++)
#pragma unroll
        for (int j = 0; j < 4; j++) acc[i][j] = (f32x4){0.f, 0.f, 0.f, 0.f};

    const int ksteps = K >> 5;
    for (int kt = 0; kt < ksteps; ++kt) {
        const int k0 = kt << 5;
#pragma unroll
        for (int r = 0; r < 2; r++) {
            const int row = (r * 4 + wave) * 16 + srow;
            __builtin_amdgcn_global_load_lds(
                (av1_t*)(A + (size_t)(tm + row) * K + k0 + scol),
                (av3_t*)(&As[row * 32 + scol]), 16, 0, 0);
            __builtin_amdgcn_global_load_lds(
                (av1_t*)(Bm + (size_t)(tn + row) * K + k0 + scol),
                (av3_t*)(&Bs[row * 32 + scol]), 16, 0, 0);
        }
        asm volatile("s_waitcnt vmcnt(0)" ::: "memory");
        __syncthreads();

        short8 af[4], bf[4];
#pragma unroll
        for (int i = 0; i < 4; i++)
            af[i] = (short8)(*(const short8_a*)&As[(wr + i * 16 + l15) * 32 + quad * 8]);
#pragma unroll
        for (int j = 0; j < 4; j++)
            bf[j] = (short8)(*(const short8_a*)&Bs[(wc + j * 16 + l15) * 32 + quad * 8]);
#pragma unroll
        for (int i = 0; i < 4; i++)
#pragma unroll
            for (int j = 0; j < 4; j++)
                acc[i][j] = __builtin_amdgcn_mfma_f32_16x16x32_bf16(af[i], bf[j], acc[i][j], 0, 0, 0);
        __syncthreads();
    }

#pragma unroll
    for (int i = 0; i < 4; i++) {
        const int row = tm + wr + i * 16 + quad * 4;
#pragma unroll
        for (int j = 0; j < 4; j++) {
            const int col = tn + wc + j * 16 + l15;
            const float bv = HAS_BIAS ? bias[col] : 0.0f;
#pragma unroll
            for (int r = 0; r < 4; r++) {
                if (OUT_F32)
                    ((float*)Cv)[(size_t)(row + r) * N + col] = acc[i][j][r] + bv;
                else
                    ((unsigned short*)Cv)[(size_t)(row + r) * N + col] = f2b(acc[i][j][r] + bv);
            }
        }
    }
}

// ---------------- 8-phase 256x256 GEMM, deep-prefetch ring (round-3 schedule) -------
// K = 2048 fixed. 512 threads = 8 waves (2 x 4), per-wave 128x64 output.
// LDS 128 KiB = 2 buffers x {A,B} x [256][64] bf16; 3-bit XOR swizzle (0 conflicts, r2).
// DEEP RING: both A and B staged a full K-tile-pair ahead.
//   prologue: A0,B0,A1,B1 (16 loads), vmcnt(8)  [retire tile-0 pair, keep tile-1 pair]
//   iter I (tiles t,t+1): stage A(t+2)h0@ph3, A(t+2)h1+B(t+2)h0@ph4, B(t+2)h1@ph5,
//                          A(t+3)h0@ph7, A(t+3)h1+B(t+3)h0+h1@ph8
//   fences: ph4 vmcnt(6)  -> retires A(t+1),B(t+1) before ph5 reads them (slack >=4 ph)
//           ph8 vmcnt(8)  -> retires A(t+2),B(t+2) before next ph1     (slack >=3 ph)
// WAR safety: every stage targets a buffer whose last reader phase completed >=1 full
// barrier-pair earlier (LA0 read ph1/2 -> staged ph3/4; LB0 read ph1/3 -> ph4/5;
// LA1 read ph5/6 -> ph7/8; LB1 read ph5/7 -> ph8).
#define LA0 0
#define LB0 16384
#define LA1 32768
#define LB1 49152

template<int NBM, int NBN, int MODE>
__global__ __launch_bounds__(512, 2)
void gemm8_kernel(const unsigned short* __restrict__ A,
                  const unsigned short* __restrict__ Bm,
                  const float* __restrict__ bias,
                  unsigned short* __restrict__ qout,
                  unsigned short* __restrict__ kvout,
                  float* __restrict__ fout)
{
    __shared__ __align__(16) unsigned short lds[65536];   // 128 KiB

    const int tid  = threadIdx.x;
    const int lane = tid & 63;
    const int wave = tid >> 6;
    const int quad = lane >> 4;
    const int l15  = lane & 15;
    const int wrow = wave >> 2;        // 0..1
    const int wcol = wave & 3;         // 0..3
    const int swz  = (l15 & 7) << 3;   // fragment-row part of the 3-bit swizzle

    // bijective chunked XCD map: NT tiles = 8 XCDs x (NT/8) consecutive column-major
    const int bid  = blockIdx.x;
    const int xcd  = bid & 7;
    const int sl   = bid >> 3;
    const int tile = xcd * (NBM * NBN / 8) + sl;
    const int bm   = tile % NBM;
    const int bn   = tile / NBM;
    const int tm   = bm * 256;
    const int tn   = bn * 256;

    const unsigned short* Ab = A  + (size_t)tm * Cn;
    const unsigned short* Bb = Bm + (size_t)tn * Cn;

    f32x4 acc[8][4];
#pragma unroll
    for (int i = 0; i < 8; i++)
#pragma unroll
        for (int j = 0; j < 4; j++) acc[i][j] = (f32x4){0.f, 0.f, 0.f, 0.f};

    // stage one 128x64 half-tile: 2 x global_load_lds(16B) per thread, linear LDS dest,
    // source k pre-permuted with the same involution the reads apply.
    auto stage = [&](const unsigned short* g, int kt, int base, int half) {
#pragma unroll
        for (int rr = 0; rr < 2; ++rr) {
            const int idx = rr * 512 + tid;            // 0..1023
            const int row = idx >> 3;                  // 0..127
            const int ks  = ((idx & 7) * 8) ^ ((row & 7) << 3);
            __builtin_amdgcn_global_load_lds(
                (av1_t*)(g + (size_t)(half * 128 + row) * Cn + kt * 64 + ks),
                (av3_t*)(lds + base + half * 8192 + idx * 8), 16, 0, 0);
        }
    };
    auto lda = [&](int base, int i, int ks) -> short8 {
        return (short8)(*(const short8_a*)&lds[base + (wrow * 128 + i * 16 + l15) * 64
                                               + ((ks * 32 + quad * 8) ^ swz)]);
    };
    auto ldb = [&](int base, int j, int ks) -> short8 {
        return (short8)(*(const short8_a*)&lds[base + (wcol * 64 + j * 16 + l15) * 64
                                               + ((ks * 32 + quad * 8) ^ swz)]);
    };

    // prologue: both tile pairs staged; retire pair 0, keep pair 1 (8 loads) in flight
    stage(Ab, 0, LA0, 0); stage(Ab, 0, LA0, 1);
    stage(Bb, 0, LB0, 0); stage(Bb, 0, LB0, 1);
    stage(Ab, 1, LA1, 0); stage(Ab, 1, LA1, 1);
    stage(Bb, 1, LB1, 0); stage(Bb, 1, LB1, 1);
    asm volatile("s_waitcnt vmcnt(8)" ::: "memory");
    __builtin_amdgcn_s_barrier();

    const int nt = Cn / 64;   // 32 K-tiles, processed 2 per iteration
    for (int t = 0; t < nt; t += 2) {
        const bool tail = (t + 2 >= nt);
        short8 af[8][2], bf[2][2];

        // ---- ph1: q1 = i[0,4) x j[0,2) on buf0 ----
#pragma unroll
        for (int i = 0; i < 4; i++) { af[i][0] = lda(LA0, i, 0); af[i][1] = lda(LA0, i, 1); }
#pragma unroll
        for (int j = 0; j < 2; j++) { bf[j][0] = ldb(LB0, j, 0); bf[j][1] = ldb(LB0, j, 1); }
        __builtin_amdgcn_s_barrier();
        asm volatile("s_waitcnt lgkmcnt(0)" ::: "memory");
        __builtin_amdgcn_s_setprio(1);
#pragma unroll
        for (int ks = 0; ks < 2; ks++)
#pragma unroll
            for (int i = 0; i < 4; i++)
#pragma unroll
                for (int j = 0; j < 2; j++)
                    acc[i][j] = __builtin_amdgcn_mfma_f32_16x16x32_bf16(af[i][ks], bf[j][ks], acc[i][j], 0, 0, 0);
        __builtin_amdgcn_s_setprio(0);
        __builtin_amdgcn_s_barrier();

        // ---- ph2: q2 = i[4,8) x j[0,2) ----
#pragma unroll
        for (int i = 4; i < 8; i++) { af[i][0] = lda(LA0, i, 0); af[i][1] = lda(LA0, i, 1); }
        __builtin_amdgcn_s_barrier();
        asm volatile("s_waitcnt lgkmcnt(0)" ::: "memory");
        __builtin_amdgcn_s_setprio(1);
#pragma unroll
        for (int ks = 0; ks < 2; ks++)
#pragma unroll
            for (int i = 4; i < 8; i++)
#pragma unroll
                for (int j = 0; j < 2; j++)
                    acc[i][j] = __builtin_amdgcn_mfma_f32_16x16x32_bf16(af[i][ks], bf[j][ks], acc[i][j], 0, 0, 0);
        __builtin_amdgcn_s_setprio(0);
        __builtin_amdgcn_s_barrier();

        // ---- ph3: q3 = i[0,4) x j[2,4); stage A(t+2)h0 -> LA0 (read done ph2) ----
#pragma unroll
        for (int j = 0; j < 2; j++) { bf[j][0] = ldb(LB0, 2 + j, 0); bf[j][1] = ldb(LB0, 2 + j, 1); }
        if (!tail) stage(Ab, t + 2, LA0, 0);
        __builtin_amdgcn_s_barrier();
        asm volatile("s_waitcnt lgkmcnt(0)" ::: "memory");
        __builtin_amdgcn_s_setprio(1);
#pragma unroll
        for (int ks = 0; ks < 2; ks++)
#pragma unroll
            for (int i = 0; i < 4; i++)
#pragma unroll
                for (int j = 0; j < 2; j++)
                    acc[i][2 + j] = __builtin_amdgcn_mfma_f32_16x16x32_bf16(af[i][ks], bf[j][ks], acc[i][2 + j], 0, 0, 0);
        __builtin_amdgcn_s_setprio(0);
        __builtin_amdgcn_s_barrier();

        // ---- ph4: q4 = i[4,8) x j[2,4); stage A(t+2)h1, B(t+2)h0; fence vmcnt(6) ----
        if (!tail) { stage(Ab, t + 2, LA0, 1); stage(Bb, t + 2, LB0, 0); }
        __builtin_amdgcn_s_barrier();
        __builtin_amdgcn_s_setprio(1);
#pragma unroll
        for (int ks = 0; ks < 2; ks++)
#pragma unroll
            for (int i = 4; i < 8; i++)
#pragma unroll
                for (int j = 0; j < 2; j++)
                    acc[i][2 + j] = __builtin_amdgcn_mfma_f32_16x16x32_bf16(af[i][ks], bf[j][ks], acc[i][2 + j], 0, 0, 0);
        __builtin_amdgcn_s_setprio(0);
        if (tail) asm volatile("s_waitcnt vmcnt(0)" ::: "memory");
        else      asm volatile("s_waitcnt vmcnt(6)" ::: "memory");
        __builtin_amdgcn_s_barrier();

        // ---- ph5: tile t+1 q1 on buf1; stage B(t+2)h1 -> LB0 (read done ph3) ----
#pragma unroll
        for (int i = 0; i < 4; i++) { af[i][0] = lda(LA1, i, 0); af[i][1] = lda(LA1, i, 1); }
#pragma unroll
        for (int j = 0; j < 2; j++) { bf[j][0] = ldb(LB1, j, 0); bf[j][1] = ldb(LB1, j, 1); }
        if (!tail) stage(Bb, t + 2, LB0, 1);
        __builtin_amdgcn_s_barrier();
        asm volatile("s_waitcnt lgkmcnt(0)" ::: "memory");
        __builtin_amdgcn_s_setprio(1);
#pragma unroll
        for (int ks = 0; ks < 2; ks++)
#pragma unroll
            for (int i = 0; i < 4; i++)
#pragma unroll
                for (int j = 0; j < 2; j++)
                    acc[i][j] = __builtin_amdgcn_mfma_f32_16x16x32_bf16(af[i][ks], bf[j][ks], acc[i][j], 0, 0, 0);
        __builtin_amdgcn_s_setprio(0);
        __builtin_amdgcn_s_barrier();

        // ---- ph6: q2 ----
#pragma unroll
        for (int i = 4; i < 8; i++) { af[i][0] = lda(LA1, i, 0); af[i][1] = lda(LA1, i, 1); }
        __builtin_amdgcn_s_barrier();
        asm volatile("s_waitcnt lgkmcnt(0)" ::: "memory");
        __builtin_amdgcn_s_setprio(1);
#pragma unroll
        for (int ks = 0; ks < 2; ks++)
#pragma unroll
            for (int i = 4; i < 8; i++)
#pragma unroll
                for (int j = 0; j < 2; j++)
                    acc[i][j] = __builtin_amdgcn_mfma_f32_16x16x32_bf16(af[i][ks], bf[j][ks], acc[i][j], 0, 0, 0);
        __builtin_amdgcn_s_setprio(0);
        __builtin_amdgcn_s_barrier();

        // ---- ph7: q3; stage A(t+3)h0 -> LA1 (read done ph6) ----
#pragma unroll
        for (int j = 0; j < 2; j++) { bf[j][0] = ldb(LB1, 2 + j, 0); bf[j][1] = ldb(LB1, 2 + j, 1); }
        if (!tail) stage(Ab, t + 3, LA1, 0);
        __builtin_amdgcn_s_barrier();
        asm volatile("s_waitcnt lgkmcnt(0)" ::: "memory");
        __builtin_amdgcn_s_setprio(1);
#pragma unroll
        for (int ks = 0; ks < 2; ks++)
#pragma unroll
            for (int i = 0; i < 4; i++)
#pragma unroll
                for (int j = 0; j < 2; j++)
                    acc[i][2 + j] = __builtin_amdgcn_mfma_f32_16x16x32_bf16(af[i][ks], bf[j][ks], acc[i][2 + j], 0, 0, 0);
        __builtin_amdgcn_s_setprio(0);
        __builtin_amdgcn_s_barrier();

        // ---- ph8: q4; stage A(t+3)h1, B(t+3)h0+h1 (LB1 read done ph7); fence vmcnt(8) ----
        if (!tail) { stage(Ab, t + 3, LA1, 1); stage(Bb, t + 3, LB1, 0); stage(Bb, t + 3, LB1, 1); }
        __builtin_amdgcn_s_barrier();
        __builtin_amdgcn_s_setprio(1);
#pragma unroll
        for (int ks = 0; ks < 2; ks++)
#pragma unroll
            for (int i = 4; i < 8; i++)
#pragma unroll
                for (int j = 0; j < 2; j++)
                    acc[i][2 + j] = __builtin_amdgcn_mfma_f32_16x16x32_bf16(af[i][ks], bf[j][ks], acc[i][2 + j], 0, 0, 0);
        __builtin_amdgcn_s_setprio(0);
        if (tail) asm volatile("s_waitcnt vmcnt(0)" ::: "memory");
        else      asm volatile("s_waitcnt vmcnt(8)" ::: "memory");
        __builtin_amdgcn_s_barrier();
    }

    if (MODE == 0) {
        // split output (q | kv), block-uniform select
        unsigned short* obase = (tn < Cn) ? qout : kvout;
        const int cofs    = (tn < Cn) ? 0 : Cn;
        const size_t ostr = (tn < Cn) ? Cn : 2 * Cn;
#pragma unroll
        for (int i = 0; i < 8; i++) {
            const int row = tm + wrow * 128 + i * 16 + quad * 4;
#pragma unroll
            for (int j = 0; j < 4; j++) {
                const int col = tn + wcol * 64 + j * 16 + l15 - cofs;
#pragma unroll
                for (int r = 0; r < 4; r++)
                    obase[(size_t)(row + r) * ostr + col] = f2b(acc[i][j][r]);
            }
        }
    } else {
        const int Nn = NBN * 256;
#pragma unroll
        for (int i = 0; i < 8; i++) {
            const int row = tm + wrow * 128 + i * 16 + quad * 4;
#pragma unroll
            for (int j = 0; j < 4; j++) {
                const int col = tn + wcol * 64 + j * 16 + l15;
                const float bv = bias[col];
#pragma unroll
                for (int r = 0; r < 4; r++)
                    fout[(size_t)(row + r) * Nn + col] = acc[i][j][r] + bv;
            }
        }
    }
}

// ---------------- flash attention: 512 threads, 8 waves x 16 Q-rows, 128-key tiles ----
// Balanced pairing (qp, 15-qp): (qp+1) + (16-qp) = 17 k-tile iters/block. Grid 8x32.
// Row-sum via MFMA against all-ones B-fragment. LDS ~102 KB (of 160 KB).
__global__ __launch_bounds__(512, 2)
void attn_kernel(const unsigned short* __restrict__ q,
                 const unsigned short* __restrict__ kv,
                 unsigned short* __restrict__ outp)
{
    __shared__ __align__(16) unsigned short Ks[128 * 136];   // [key][d], stride 136
    __shared__ __align__(16) unsigned short Vs[128 * 136];   // [d][pcol] swizzled, stride 136
    __shared__ __align__(16) unsigned short Ps[8][16 * 136]; // per-wave P (16 rows x 128 keys)

    const int qp   = blockIdx.x;          // q pair index (0..7)
    const int bh   = blockIdx.y;          // b*H + h (32)
    const int b    = bh >> 4;
    const int h    = bh & 15;
    const int tid  = threadIdx.x;
    const int lane = tid & 63;
    const int wave = tid >> 6;            // 0..7
    const int quad = lane >> 4;
    const int l15  = lane & 15;

    short8 ones;
#pragma unroll
    for (int e = 0; e < 8; e++) ones[e] = (short)0x3F80;   // bf16 1.0

    for (int half = 0; half < 2; ++half) {
        const int qt = half ? (15 - qp) : qp;
        const int qrow0 = qt * 128 + wave * 16;

        // Q A-fragments: rows qrow0 + l15, A[m=l15][k=quad*8+j]
        short8 qf[4];
#pragma unroll
        for (int kk = 0; kk < 4; kk++) {
            const unsigned short* p = q + (size_t)(b * Tn + qrow0 + l15) * Cn
                                      + h * HDn + kk * 32 + quad * 8;
            qf[kk] = (short8)(*(const short8_a*)p);
        }

        float m_i[4], l_i[4];
        f32x4 o_acc[8];
#pragma unroll
        for (int r = 0; r < 4; r++) { m_i[r] = -1e30f; l_i[r] = 0.f; }
#pragma unroll
        for (int jd = 0; jd < 8; jd++) o_acc[jd] = (f32x4){0.f, 0.f, 0.f, 0.f};

        const int ktiles = qt + 1;   // 128-key tiles, causal

        u32x4_a kr[4], vr[4];
        auto preload = [&](int kt2) {
            const int kk0 = kt2 * 128;
#pragma unroll
            for (int rep = 0; rep < 4; ++rep) {
                const int idx  = tid + rep * 512;     // 0..2047
                const int krow = idx >> 4;            // 0..127
                const int dg   = (idx & 15) * 8;
                const size_t rb = (size_t)(b * Tn + kk0 + krow) * (2 * Cn) + h * HDn + dg;
                kr[rep] = *(const u32x4_a*)(kv + rb);
                vr[rep] = *(const u32x4_a*)(kv + rb + Cn);
            }
        };
        preload(0);

        for (int kt2 = 0; kt2 < ktiles; ++kt2) {
            const int kk0 = kt2 * 128;
            __syncthreads();
            // stage K natural (b128), V transposed + XOR-swizzled (scalar b16)
#pragma unroll
            for (int rep = 0; rep < 4; ++rep) {
                const int idx  = tid + rep * 512;
                const int krow = idx >> 4;
                const int l    = idx & 15;
                const int dg   = l * 8;
                *(u32x4_a*)&Ks[krow * 136 + dg] = kr[rep];
                const int pcol = krow ^ ((l & 7) << 3);
                const unsigned short* ve = (const unsigned short*)&vr[rep];
#pragma unroll
                for (int e = 0; e < 8; e++) Vs[(dg + e) * 136 + pcol] = ve[e];
            }
            __syncthreads();
            if (kt2 + 1 < ktiles) preload(kt2 + 1);

            // S = Q K^T : 16 q-rows x 128 keys (8 j-frags), 4 k-steps over HD=128
            f32x4 s[8];
#pragma unroll
            for (int j = 0; j < 8; j++) s[j] = (f32x4){0.f, 0.f, 0.f, 0.f};
#pragma unroll
            for (int kk = 0; kk < 4; ++kk) {
                short8 kf[8];
#pragma unroll
                for (int j = 0; j < 8; j++)
                    kf[j] = (short8)(*(const short8_a*)&Ks[(j * 16 + l15) * 136 + kk * 32 + quad * 8]);
#pragma unroll
                for (int j = 0; j < 8; j++)
                    s[j] = __builtin_amdgcn_mfma_f32_16x16x32_bf16(qf[kk], kf[j], s[j], 0, 0, 0);
            }

            // online softmax: row = quad*4+r, col = j*16+l15
            const bool needmask = (kk0 + 127 > qrow0);  // wave-uniform (diagonal tile only)
            float alr[4];
#pragma unroll
            for (int r = 0; r < 4; r++) {
                const int qidx = qrow0 + quad * 4 + r;
                float mx = -1e30f;
#pragma unroll
                for (int j = 0; j < 8; j++) {
                    float v = s[j][r] * 0.08838834764831845f;
                    if (needmask) {
                        const int kidx = kk0 + j * 16 + l15;
                        v = (kidx <= qidx) ? v : -1e30f;
                    }
                    s[j][r] = v;
                    mx = fmaxf(mx, v);
                }
#pragma unroll
                for (int off = 1; off < 16; off <<= 1)
                    mx = fmaxf(mx, __shfl_xor(mx, off));
                const float mn = fmaxf(m_i[r], mx);
                alr[r] = __expf(fminf(m_i[r] - mn, 0.f));
                m_i[r] = mn;
#pragma unroll
                for (int j = 0; j < 8; j++) {
                    const float p = __expf(fminf(s[j][r] - mn, 0.f));
                    s[j][r] = p;
                }
#pragma unroll
                for (int jd = 0; jd < 8; jd++) o_acc[jd][r] *= alr[r];
#pragma unroll
                for (int j = 0; j < 8; j++)
                    Ps[wave][(quad * 4 + r) * 136 + j * 16 + l15] = f2b(s[j][r]);
            }
            // Ps region is per-wave: drain this wave's LDS writes, no block barrier
            asm volatile("s_waitcnt lgkmcnt(0)" ::: "memory");

            // O += P V ; row-sum via ones-MFMA (l-layout: every col = rowsum)
            f32x4 lacc = (f32x4){0.f, 0.f, 0.f, 0.f};
#pragma unroll
            for (int kk2 = 0; kk2 < 4; ++kk2) {
                short8 pf = (short8)(*(const short8_a*)&Ps[wave][l15 * 136 + kk2 * 32 + quad * 8]);
#pragma unroll
                for (int jd = 0; jd < 8; jd++) {
                    const int d = jd * 16 + l15;
                    const int g = (d >> 3) & 7;
                    const int colb = ((4 * kk2 + quad) ^ g) * 8;
                    short8 vf = (short8)(*(const short8_a*)&Vs[d * 136 + colb]);
                    o_acc[jd] = __builtin_amdgcn_mfma_f32_16x16x32_bf16(pf, vf, o_acc[jd], 0, 0, 0);
                }
                lacc = __builtin_amdgcn_mfma_f32_16x16x32_bf16(pf, ones, lacc, 0, 0, 0);
            }
#pragma unroll
            for (int r = 0; r < 4; r++)
                l_i[r] = l_i[r] * alr[r] + lacc[r];
        }

        // epilogue: out[b*T + t, h*128 + d] = o/l  (overwrites this block's own q — safe)
#pragma unroll
        for (int r = 0; r < 4; r++) {
            const float inv = 1.0f / fmaxf(l_i[r], 1e-20f);
            const int trow = qrow0 + quad * 4 + r;
#pragma unroll
            for (int jd = 0; jd < 8; jd++) {
                const int col = h * HDn + jd * 16 + l15;
                outp[(size_t)(b * Tn + trow) * Cn + col] = f2b(o_acc[jd][r] * inv);
            }
        }
    }
}

extern "C" void kernel_launch(void* const* d_in, const int* in_sizes, int n_in,
                              void* d_out, int out_size, void* d_ws, size_t ws_size,
                              hipStream_t stream)
{
    const float* x      = (const float*)d_in[0]; // [B,T,C]  fp32
    const float* w_attn = (const float*)d_in[1]; // [3C,C]   fp32
    const float* w_proj = (const float*)d_in[2]; // [C,C]    fp32
    const float* b_proj = (const float*)d_in[3]; // [C]      fp32
    float* out = (float*)d_out;                  // [B,T,C]  fp32 (32 MiB)

    const size_t MiB = 1024 * 1024;
    unsigned short* kvbuf = (unsigned short*)d_out;   // [4096,4096] bf16 scratch in d_out

    const int nx   = Bn * Tn * Cn;         // 8.4M
    const int nwq  = Cn * Cn;              // 4.2M
    const int nwkv = 2 * Cn * Cn;          // 8.4M

    if (ws_size >= 56 * MiB) {
        // FUSED PATH: xb [0,16M) | qbuf [16M,32M) | wb [32M,56M) holds full w_attn bf16
        unsigned short* xb   = (unsigned short*)d_ws;
        unsigned short* qbuf = (unsigned short*)((char*)d_ws + 16 * MiB);
        unsigned short* wb   = (unsigned short*)((char*)d_ws + 32 * MiB);
        const int nwa = 3 * Cn * Cn;       // 12.6M

        cvt_kernel<<<nx / 8 / 256, 256, 0, stream>>>(x, xb, nx);
        cvt_kernel<<<nwa / 8 / 256, 256, 0, stream>>>(w_attn, wb, nwa);
        gemm8_kernel<16, 24, 0><<<dim3(384), 512, 0, stream>>>(xb, wb, nullptr,
                                                               qbuf, kvbuf, nullptr);
        attn_kernel<<<dim3(8, Bn * Hn), 512, 0, stream>>>(qbuf, kvbuf, qbuf);
        cvt_kernel<<<nwq / 8 / 256, 256, 0, stream>>>(w_proj, wb, nwq);
        gemm_bb_kernel<1, 1><<<dim3(32, 16), 256, 0, stream>>>(qbuf, wb, b_proj, out,
                                                               Bn * Tn, Cn, Cn);
    } else {
        // 48-MiB PATH (rounds 5-6 proven): xb | qbuf | wb(16M, chunked weights)
        unsigned short* xb   = (unsigned short*)d_ws;
        unsigned short* qbuf = (unsigned short*)((char*)d_ws + 16 * MiB);
        unsigned short* wb   = (unsigned short*)((char*)d_ws + 32 * MiB);

        cvt_kernel<<<nx / 8 / 256, 256, 0, stream>>>(x, xb, nx);
        cvt_kernel<<<nwq / 8 / 256, 256, 0, stream>>>(w_attn, wb, nwq);
        gemm_bb_kernel<0, 0><<<dim3(32, 16), 256, 0, stream>>>(xb, wb, nullptr, qbuf,
                                                               Bn * Tn, Cn, Cn);
        cvt_kernel<<<nwkv / 8 / 256, 256, 0, stream>>>(w_attn + (size_t)Cn * Cn, wb, nwkv);
        gemm_bb_kernel<0, 0><<<dim3(32, 32), 256, 0, stream>>>(xb, wb, nullptr, kvbuf,
                                                               Bn * Tn, 2 * Cn, Cn);
        attn_kernel<<<dim3(8, Bn * Hn), 512, 0, stream>>>(qbuf, kvbuf, qbuf);
        cvt_kernel<<<nwq / 8 / 256, 256, 0, stream>>>(w_proj, wb, nwq);
        gemm_bb_kernel<1, 1><<<dim3(32, 16), 256, 0, stream>>>(qbuf, wb, b_proj, out,
                                                               Bn * Tn, Cn, Cn);
    }
}

// Round 4
// 381.880 us; speedup vs baseline: 1.2560x; 1.2560x over previous
//
#include <hip/hip_runtime.h>
#include <hip/hip_bf16.h>
#include <stdint.h>
#include <stddef.h>

// Problem constants
#define Bn  2
#define Tn  2048
#define Cn  2048
#define Hn  16
#define HDn 128

// may_alias vector types for memory access (TBAA-safe); plain short8 for MFMA args
typedef short short8   __attribute__((ext_vector_type(8)));
typedef short short8_a __attribute__((ext_vector_type(8), may_alias));
typedef unsigned int u32x4_a __attribute__((ext_vector_type(4), may_alias));
typedef unsigned short u16x4_a __attribute__((ext_vector_type(4), may_alias));
typedef unsigned short u16x8_a __attribute__((ext_vector_type(8), may_alias));
typedef float f32x4 __attribute__((ext_vector_type(4)));

// address-space-qualified void for global_load_lds
typedef __attribute__((address_space(1))) const void av1_t;
typedef __attribute__((address_space(3))) void av3_t;

__device__ inline unsigned short f2b(float f) {
    union { float f; unsigned u; } v; v.f = f;
    unsigned r = v.u + 0x7fffu + ((v.u >> 16) & 1u);   // RNE
    return (unsigned short)(r >> 16);
}
__device__ inline u16x4_a cvt4_f32_bf16(u32x4_a v) {
    u16x4_a h;
#pragma unroll
    for (int e = 0; e < 4; e++) {
        unsigned u = v[e];
        unsigned r = u + 0x7fffu + ((u >> 16) & 1u);
        h[e] = (unsigned short)(r >> 16);
    }
    return h;
}

// ---------------- fp32 -> bf16 bulk convert (memory-bound) ----------------
__global__ __launch_bounds__(256)
void cvt_kernel(const float* __restrict__ src, unsigned short* __restrict__ dst, int n)
{
    const int i = (blockIdx.x * 256 + threadIdx.x) * 8;
    if (i >= n) return;
    u32x4_a a = *(const u32x4_a*)((const unsigned*)src + i);
    u32x4_a b = *(const u32x4_a*)((const unsigned*)src + i + 4);
    u16x8_a o;
    u16x4_a ha = cvt4_f32_bf16(a), hb = cvt4_f32_bf16(b);
#pragma unroll
    for (int e = 0; e < 4; e++) { o[e] = ha[e]; o[e + 4] = hb[e]; }
    *(u16x8_a*)(dst + i) = o;
}

// ---------------- pure-bf16 GEMM, m97-style global_load_lds staging ----------------
// Proven ~50 us for the proj GEMM at grid(32,16)x256thr (512 blocks, 2 blk/CU).
template<int OUT_F32, int HAS_BIAS>
__global__ __launch_bounds__(256)
void gemm_bb_kernel(const unsigned short* __restrict__ A,
                    const unsigned short* __restrict__ Bm,
                    const float* __restrict__ bias, void* __restrict__ Cv,
                    int M, int N, int K)
{
    __shared__ __align__(16) unsigned short As[128 * 32];
    __shared__ __align__(16) unsigned short Bs[128 * 32];

    const int tid  = threadIdx.x;
    const int lane = tid & 63;
    const int wave = tid >> 6;
    const int quad = lane >> 4;
    const int l15  = lane & 15;
    const int tm = blockIdx.x * 128;
    const int tn = blockIdx.y * 128;
    const int wr = (wave >> 1) * 64;
    const int wc = (wave & 1) * 64;

    const int srow = lane >> 2;
    const int scol = (lane & 3) * 8;

    f32x4 acc[4][4];
#pragma unroll
    for (int i = 0; i < 4; i++)
#pragma unroll
        for (int j = 0; j < 4; j++) acc[i][j] = (f32x4){0.f, 0.f, 0.f, 0.f};

    const int ksteps = K >> 5;
    for (int kt = 0; kt < ksteps; ++kt) {
        const int k0 = kt << 5;
#pragma unroll
        for (int r = 0; r < 2; r++) {
            const int row = (r * 4 + wave) * 16 + srow;
            __builtin_amdgcn_global_load_lds(
                (av1_t*)(A + (size_t)(tm + row) * K + k0 + scol),
                (av3_t*)(&As[row * 32 + scol]), 16, 0, 0);
            __builtin_amdgcn_global_load_lds(
                (av1_t*)(Bm + (size_t)(tn + row) * K + k0 + scol),
                (av3_t*)(&Bs[row * 32 + scol]), 16, 0, 0);
        }
        asm volatile("s_waitcnt vmcnt(0)" ::: "memory");
        __syncthreads();

        short8 af[4], bf[4];
#pragma unroll
        for (int i = 0; i < 4; i++)
            af[i] = (short8)(*(const short8_a*)&As[(wr + i * 16 + l15) * 32 + quad * 8]);
#pragma unroll
        for (int j = 0; j < 4; j++)
            bf[j] = (short8)(*(const short8_a*)&Bs[(wc + j * 16 + l15) * 32 + quad * 8]);
#pragma unroll
        for (int i = 0; i < 4; i++)
#pragma unroll
            for (int j = 0; j < 4; j++)
                acc[i][j] = __builtin_amdgcn_mfma_f32_16x16x32_bf16(af[i], bf[j], acc[i][j], 0, 0, 0);
        __syncthreads();
    }

#pragma unroll
    for (int i = 0; i < 4; i++) {
        const int row = tm + wr + i * 16 + quad * 4;
#pragma unroll
        for (int j = 0; j < 4; j++) {
            const int col = tn + wc + j * 16 + l15;
            const float bv = HAS_BIAS ? bias[col] : 0.0f;
#pragma unroll
            for (int r = 0; r < 4; r++) {
                if (OUT_F32)
                    ((float*)Cv)[(size_t)(row + r) * N + col] = acc[i][j][r] + bv;
                else
                    ((unsigned short*)Cv)[(size_t)(row + r) * N + col] = f2b(acc[i][j][r] + bv);
            }
        }
    }
}

// ---------------- qkv GEMM: 256x192 tile, 8-phase, round-2-proven shallow ring ------
// M=4096, N=6144, K=2048. Grid 512 = 16(bm) x 32(bn) -> EXACTLY 2 full CU rounds
// (fixes round-2's 75% tail). 512 threads = 8 waves (2x4), per-wave 128x48 (8x3 frags).
// LDS 112 KiB: A [256][64] x2buf, B [192][64] x2buf; 3-bit XOR swizzle (0 conflicts, r2).
// Ring (= round-2's proven shape; round-3's deep ring REGRESSED and is reverted):
//   prologue: A0,B0,A1 (11 loads), vmcnt(4) -> retire tile-0, keep A1 in flight
//   ph1/2/3: stage B(t+1) thirds -> LB1 ; ph4: stage A(t+2) -> LA0, fence vmcnt(4)
//   ph5/6/7: stage B(t+2) thirds -> LB0 ; ph8: stage A(t+3) -> LA1, fence vmcnt(4)
//   (<=11 outstanding, evenly paced ~1 stage call/phase; FIFO retire sets verified)
// MFMA per tile: ph 16/16/8/8 (j-frags {0,1} then {2}).
#define LA0 0
#define LB0 16384
#define LA1 28672
#define LB1 45056

__global__ __launch_bounds__(512, 2)
void gemm_qkv192_kernel(const unsigned short* __restrict__ A,
                        const unsigned short* __restrict__ Bm,
                        unsigned short* __restrict__ qout,
                        unsigned short* __restrict__ kvout)
{
    __shared__ __align__(16) unsigned short lds[57344];   // 112 KiB

    const int tid  = threadIdx.x;
    const int lane = tid & 63;
    const int wave = tid >> 6;
    const int quad = lane >> 4;
    const int l15  = lane & 15;
    const int wrow = wave >> 2;        // 0..1
    const int wcol = wave & 3;         // 0..3
    const int swz  = (l15 & 7) << 3;   // 3-bit XOR swizzle, 16B granule over 128B row

    // bijective chunked XCD map: 512 blocks = 8 XCDs x 64; per XCD: 4 bn-columns x 16 bm
    const int bid  = blockIdx.x;
    const int xcd  = bid & 7;
    const int sl   = bid >> 3;                 // 0..63
    const int tile = xcd * 64 + sl;
    const int bm   = tile & 15;
    const int bn   = tile >> 4;                // 0..31
    const int tm   = bm * 256;
    const int tn   = bn * 192;

    const unsigned short* Ab = A  + (size_t)tm * Cn;
    const unsigned short* Bb = Bm + (size_t)tn * Cn;

    f32x4 acc[8][3];
#pragma unroll
    for (int i = 0; i < 8; i++)
#pragma unroll
        for (int j = 0; j < 3; j++) acc[i][j] = (f32x4){0.f, 0.f, 0.f, 0.f};

    // A half-tile (128 rows): 2 x global_load_lds(16B)/thread; linear LDS dest,
    // source col pre-permuted with the involution the reads apply.
    auto stageA = [&](int kt, int base, int half) {
#pragma unroll
        for (int rr = 0; rr < 2; ++rr) {
            const int idx = rr * 512 + tid;            // 0..1023
            const int row = idx >> 3;                  // 0..127
            const int ks  = ((idx & 7) * 8) ^ ((row & 7) << 3);
            __builtin_amdgcn_global_load_lds(
                (av1_t*)(Ab + (size_t)(half * 128 + row) * Cn + kt * 64 + ks),
                (av3_t*)(lds + base + half * 8192 + idx * 8), 16, 0, 0);
        }
    };
    // B third-tile (64 rows): 1 x global_load_lds(16B)/thread
    auto stageB = [&](int kt, int base, int third) {
        const int row = third * 64 + (tid >> 3);       // 0..191
        const int ks  = ((tid & 7) * 8) ^ ((row & 7) << 3);
        __builtin_amdgcn_global_load_lds(
            (av1_t*)(Bb + (size_t)row * Cn + kt * 64 + ks),
            (av3_t*)(lds + base + third * 4096 + tid * 8), 16, 0, 0);
    };
    auto lda = [&](int base, int i, int ks) -> short8 {
        return (short8)(*(const short8_a*)&lds[base + (wrow * 128 + i * 16 + l15) * 64
                                               + ((ks * 32 + quad * 8) ^ swz)]);
    };
    auto ldb = [&](int base, int j, int ks) -> short8 {
        return (short8)(*(const short8_a*)&lds[base + (wcol * 48 + j * 16 + l15) * 64
                                               + ((ks * 32 + quad * 8) ^ swz)]);
    };

    // prologue: tile0 (A,B) -> buf0, tile1.A -> buf1; retire tile0 (7), keep A1 (4)
    stageA(0, LA0, 0); stageA(0, LA0, 1);
    stageB(0, LB0, 0); stageB(0, LB0, 1); stageB(0, LB0, 2);
    stageA(1, LA1, 0); stageA(1, LA1, 1);
    asm volatile("s_waitcnt vmcnt(4)" ::: "memory");
    __builtin_amdgcn_s_barrier();

    const int nt = Cn / 64;   // 32 K-tiles, processed 2 per iteration
    for (int t = 0; t < nt; t += 2) {
        const bool tail = (t + 2 >= nt);
        short8 af[8][2], bf[2][2], bf2[2];

        // ---- ph1: i[0,4) x j[0,2) on buf0; stage B(t+1)t0 -> LB1 ----
#pragma unroll
        for (int i = 0; i < 4; i++) { af[i][0] = lda(LA0, i, 0); af[i][1] = lda(LA0, i, 1); }
#pragma unroll
        for (int j = 0; j < 2; j++) { bf[j][0] = ldb(LB0, j, 0); bf[j][1] = ldb(LB0, j, 1); }
        stageB(t + 1, LB1, 0);
        __builtin_amdgcn_s_barrier();
        asm volatile("s_waitcnt lgkmcnt(0)" ::: "memory");
        __builtin_amdgcn_s_setprio(1);
#pragma unroll
        for (int ks = 0; ks < 2; ks++)
#pragma unroll
            for (int i = 0; i < 4; i++)
#pragma unroll
                for (int j = 0; j < 2; j++)
                    acc[i][j] = __builtin_amdgcn_mfma_f32_16x16x32_bf16(af[i][ks], bf[j][ks], acc[i][j], 0, 0, 0);
        __builtin_amdgcn_s_setprio(0);
        __builtin_amdgcn_s_barrier();

        // ---- ph2: i[4,8) x j[0,2); stage B(t+1)t1 ----
#pragma unroll
        for (int i = 4; i < 8; i++) { af[i][0] = lda(LA0, i, 0); af[i][1] = lda(LA0, i, 1); }
        stageB(t + 1, LB1, 1);
        __builtin_amdgcn_s_barrier();
        asm volatile("s_waitcnt lgkmcnt(0)" ::: "memory");
        __builtin_amdgcn_s_setprio(1);
#pragma unroll
        for (int ks = 0; ks < 2; ks++)
#pragma unroll
            for (int i = 4; i < 8; i++)
#pragma unroll
                for (int j = 0; j < 2; j++)
                    acc[i][j] = __builtin_amdgcn_mfma_f32_16x16x32_bf16(af[i][ks], bf[j][ks], acc[i][j], 0, 0, 0);
        __builtin_amdgcn_s_setprio(0);
        __builtin_amdgcn_s_barrier();

        // ---- ph3: i[0,4) x j=2; stage B(t+1)t2 ----
        bf2[0] = ldb(LB0, 2, 0); bf2[1] = ldb(LB0, 2, 1);
        stageB(t + 1, LB1, 2);
        __builtin_amdgcn_s_barrier();
        asm volatile("s_waitcnt lgkmcnt(0)" ::: "memory");
        __builtin_amdgcn_s_setprio(1);
#pragma unroll
        for (int ks = 0; ks < 2; ks++)
#pragma unroll
            for (int i = 0; i < 4; i++)
                acc[i][2] = __builtin_amdgcn_mfma_f32_16x16x32_bf16(af[i][ks], bf2[ks], acc[i][2], 0, 0, 0);
        __builtin_amdgcn_s_setprio(0);
        __builtin_amdgcn_s_barrier();

        // ---- ph4: i[4,8) x j=2; stage A(t+2) -> LA0 (reads done ph2); fence ----
        if (!tail) { stageA(t + 2, LA0, 0); stageA(t + 2, LA0, 1); }
        __builtin_amdgcn_s_barrier();
        __builtin_amdgcn_s_setprio(1);
#pragma unroll
        for (int ks = 0; ks < 2; ks++)
#pragma unroll
            for (int i = 4; i < 8; i++)
                acc[i][2] = __builtin_amdgcn_mfma_f32_16x16x32_bf16(af[i][ks], bf2[ks], acc[i][2], 0, 0, 0);
        __builtin_amdgcn_s_setprio(0);
        if (tail) asm volatile("s_waitcnt vmcnt(0)" ::: "memory");
        else      asm volatile("s_waitcnt vmcnt(4)" ::: "memory");
        __builtin_amdgcn_s_barrier();

        // ---- ph5: tile t+1 on buf1, i[0,4) x j[0,2); stage B(t+2)t0 -> LB0 ----
#pragma unroll
        for (int i = 0; i < 4; i++) { af[i][0] = lda(LA1, i, 0); af[i][1] = lda(LA1, i, 1); }
#pragma unroll
        for (int j = 0; j < 2; j++) { bf[j][0] = ldb(LB1, j, 0); bf[j][1] = ldb(LB1, j, 1); }
        if (!tail) stageB(t + 2, LB0, 0);
        __builtin_amdgcn_s_barrier();
        asm volatile("s_waitcnt lgkmcnt(0)" ::: "memory");
        __builtin_amdgcn_s_setprio(1);
#pragma unroll
        for (int ks = 0; ks < 2; ks++)
#pragma unroll
            for (int i = 0; i < 4; i++)
#pragma unroll
                for (int j = 0; j < 2; j++)
                    acc[i][j] = __builtin_amdgcn_mfma_f32_16x16x32_bf16(af[i][ks], bf[j][ks], acc[i][j], 0, 0, 0);
        __builtin_amdgcn_s_setprio(0);
        __builtin_amdgcn_s_barrier();

        // ---- ph6: i[4,8) x j[0,2); stage B(t+2)t1 ----
#pragma unroll
        for (int i = 4; i < 8; i++) { af[i][0] = lda(LA1, i, 0); af[i][1] = lda(LA1, i, 1); }
        if (!tail) stageB(t + 2, LB0, 1);
        __builtin_amdgcn_s_barrier();
        asm volatile("s_waitcnt lgkmcnt(0)" ::: "memory");
        __builtin_amdgcn_s_setprio(1);
#pragma unroll
        for (int ks = 0; ks < 2; ks++)
#pragma unroll
            for (int i = 4; i < 8; i++)
#pragma unroll
                for (int j = 0; j < 2; j++)
                    acc[i][j] = __builtin_amdgcn_mfma_f32_16x16x32_bf16(af[i][ks], bf[j][ks], acc[i][j], 0, 0, 0);
        __builtin_amdgcn_s_setprio(0);
        __builtin_amdgcn_s_barrier();

        // ---- ph7: i[0,4) x j=2; stage B(t+2)t2 ----
        bf2[0] = ldb(LB1, 2, 0); bf2[1] = ldb(LB1, 2, 1);
        if (!tail) stageB(t + 2, LB0, 2);
        __builtin_amdgcn_s_barrier();
        asm volatile("s_waitcnt lgkmcnt(0)" ::: "memory");
        __builtin_amdgcn_s_setprio(1);
#pragma unroll
        for (int ks = 0; ks < 2; ks++)
#pragma unroll
            for (int i = 0; i < 4; i++)
                acc[i][2] = __builtin_amdgcn_mfma_f32_16x16x32_bf16(af[i][ks], bf2[ks], acc[i][2], 0, 0, 0);
        __builtin_amdgcn_s_setprio(0);
        __builtin_amdgcn_s_barrier();

        // ---- ph8: i[4,8) x j=2; stage A(t+3) -> LA1 (reads done ph6); fence ----
        if (!tail) { stageA(t + 3, LA1, 0); stageA(t + 3, LA1, 1); }
        __builtin_amdgcn_s_barrier();
        __builtin_amdgcn_s_setprio(1);
#pragma unroll
        for (int ks = 0; ks < 2; ks++)
#pragma unroll
            for (int i = 4; i < 8; i++)
                acc[i][2] = __builtin_amdgcn_mfma_f32_16x16x32_bf16(af[i][ks], bf2[ks], acc[i][2], 0, 0, 0);
        __builtin_amdgcn_s_setprio(0);
        if (tail) asm volatile("s_waitcnt vmcnt(0)" ::: "memory");
        else      asm volatile("s_waitcnt vmcnt(4)" ::: "memory");
        __builtin_amdgcn_s_barrier();
    }

    // epilogue: per-element q|kv select (192 doesn't divide the 2048 boundary evenly)
#pragma unroll
    for (int i = 0; i < 8; i++) {
        const int row = tm + wrow * 128 + i * 16 + quad * 4;
#pragma unroll
        for (int j = 0; j < 3; j++) {
            const int c = tn + wcol * 48 + j * 16 + l15;
#pragma unroll
            for (int r = 0; r < 4; r++) {
                const unsigned short hb = f2b(acc[i][j][r]);
                if (c < Cn) qout[(size_t)(row + r) * Cn + c] = hb;
                else        kvout[(size_t)(row + r) * (2 * Cn) + (c - Cn)] = hb;
            }
        }
    }
}

// ---------------- flash attention: 512 threads, 8 waves x 16 Q-rows, 128-key tiles ----
// Balanced pairing (qp, 15-qp): (qp+1) + (16-qp) = 17 k-tile iters/block. Grid 8x32.
// Row-sum via MFMA against all-ones B-fragment. LDS ~102 KB (of 160 KB).
__global__ __launch_bounds__(512, 2)
void attn_kernel(const unsigned short* __restrict__ q,
                 const unsigned short* __restrict__ kv,
                 unsigned short* __restrict__ outp)
{
    __shared__ __align__(16) unsigned short Ks[128 * 136];   // [key][d], stride 136
    __shared__ __align__(16) unsigned short Vs[128 * 136];   // [d][pcol] swizzled, stride 136
    __shared__ __align__(16) unsigned short Ps[8][16 * 136]; // per-wave P (16 rows x 128 keys)

    const int qp   = blockIdx.x;          // q pair index (0..7)
    const int bh   = blockIdx.y;          // b*H + h (32)
    const int b    = bh >> 4;
    const int h    = bh & 15;
    const int tid  = threadIdx.x;
    const int lane = tid & 63;
    const int wave = tid >> 6;            // 0..7
    const int quad = lane >> 4;
    const int l15  = lane & 15;

    short8 ones;
#pragma unroll
    for (int e = 0; e < 8; e++) ones[e] = (short)0x3F80;   // bf16 1.0

    for (int half = 0; half < 2; ++half) {
        const int qt = half ? (15 - qp) : qp;
        const int qrow0 = qt * 128 + wave * 16;

        // Q A-fragments: rows qrow0 + l15, A[m=l15][k=quad*8+j]
        short8 qf[4];
#pragma unroll
        for (int kk = 0; kk < 4; kk++) {
            const unsigned short* p = q + (size_t)(b * Tn + qrow0 + l15) * Cn
                                      + h * HDn + kk * 32 + quad * 8;
            qf[kk] = (short8)(*(const short8_a*)p);
        }

        float m_i[4], l_i[4];
        f32x4 o_acc[8];
#pragma unroll
        for (int r = 0; r < 4; r++) { m_i[r] = -1e30f; l_i[r] = 0.f; }
#pragma unroll
        for (int jd = 0; jd < 8; jd++) o_acc[jd] = (f32x4){0.f, 0.f, 0.f, 0.f};

        const int ktiles = qt + 1;   // 128-key tiles, causal

        u32x4_a kr[4], vr[4];
        auto preload = [&](int kt2) {
            const int kk0 = kt2 * 128;
#pragma unroll
            for (int rep = 0; rep < 4; ++rep) {
                const int idx  = tid + rep * 512;     // 0..2047
                const int krow = idx >> 4;            // 0..127
                const int dg   = (idx & 15) * 8;
                const size_t rb = (size_t)(b * Tn + kk0 + krow) * (2 * Cn) + h * HDn + dg;
                kr[rep] = *(const u32x4_a*)(kv + rb);
                vr[rep] = *(const u32x4_a*)(kv + rb + Cn);
            }
        };
        preload(0);

        for (int kt2 = 0; kt2 < ktiles; ++kt2) {
            const int kk0 = kt2 * 128;
            __syncthreads();
            // stage K natural (b128), V transposed + XOR-swizzled (scalar b16)
#pragma unroll
            for (int rep = 0; rep < 4; ++rep) {
                const int idx  = tid + rep * 512;
                const int krow = idx >> 4;
                const int l    = idx & 15;
                const int dg   = l * 8;
                *(u32x4_a*)&Ks[krow * 136 + dg] = kr[rep];
                const int pcol = krow ^ ((l & 7) << 3);
                const unsigned short* ve = (const unsigned short*)&vr[rep];
#pragma unroll
                for (int e = 0; e < 8; e++) Vs[(dg + e) * 136 + pcol] = ve[e];
            }
            __syncthreads();
            if (kt2 + 1 < ktiles) preload(kt2 + 1);

            // S = Q K^T : 16 q-rows x 128 keys (8 j-frags), 4 k-steps over HD=128
            f32x4 s[8];
#pragma unroll
            for (int j = 0; j < 8; j++) s[j] = (f32x4){0.f, 0.f, 0.f, 0.f};
#pragma unroll
            for (int kk = 0; kk < 4; ++kk) {
                short8 kf[8];
#pragma unroll
                for (int j = 0; j < 8; j++)
                    kf[j] = (short8)(*(const short8_a*)&Ks[(j * 16 + l15) * 136 + kk * 32 + quad * 8]);
#pragma unroll
                for (int j = 0; j < 8; j++)
                    s[j] = __builtin_amdgcn_mfma_f32_16x16x32_bf16(qf[kk], kf[j], s[j], 0, 0, 0);
            }

            // online softmax: row = quad*4+r, col = j*16+l15
            const bool needmask = (kk0 + 127 > qrow0);  // wave-uniform (diagonal tile only)
            float alr[4];
#pragma unroll
            for (int r = 0; r < 4; r++) {
                const int qidx = qrow0 + quad * 4 + r;
                float mx = -1e30f;
#pragma unroll
                for (int j = 0; j < 8; j++) {
                    float v = s[j][r] * 0.08838834764831845f;
                    if (needmask) {
                        const int kidx = kk0 + j * 16 + l15;
                        v = (kidx <= qidx) ? v : -1e30f;
                    }
                    s[j][r] = v;
                    mx = fmaxf(mx, v);
                }
#pragma unroll
                for (int off = 1; off < 16; off <<= 1)
                    mx = fmaxf(mx, __shfl_xor(mx, off));
                const float mn = fmaxf(m_i[r], mx);
                alr[r] = __expf(fminf(m_i[r] - mn, 0.f));
                m_i[r] = mn;
#pragma unroll
                for (int j = 0; j < 8; j++) {
                    const float p = __expf(fminf(s[j][r] - mn, 0.f));
                    s[j][r] = p;
                }
#pragma unroll
                for (int jd = 0; jd < 8; jd++) o_acc[jd][r] *= alr[r];
#pragma unroll
                for (int j = 0; j < 8; j++)
                    Ps[wave][(quad * 4 + r) * 136 + j * 16 + l15] = f2b(s[j][r]);
            }
            // Ps region is per-wave: drain this wave's LDS writes, no block barrier
            asm volatile("s_waitcnt lgkmcnt(0)" ::: "memory");

            // O += P V ; row-sum via ones-MFMA (l-layout: every col = rowsum)
            f32x4 lacc = (f32x4){0.f, 0.f, 0.f, 0.f};
#pragma unroll
            for (int kk2 = 0; kk2 < 4; ++kk2) {
                short8 pf = (short8)(*(const short8_a*)&Ps[wave][l15 * 136 + kk2 * 32 + quad * 8]);
#pragma unroll
                for (int jd = 0; jd < 8; jd++) {
                    const int d = jd * 16 + l15;
                    const int g = (d >> 3) & 7;
                    const int colb = ((4 * kk2 + quad) ^ g) * 8;
                    short8 vf = (short8)(*(const short8_a*)&Vs[d * 136 + colb]);
                    o_acc[jd] = __builtin_amdgcn_mfma_f32_16x16x32_bf16(pf, vf, o_acc[jd], 0, 0, 0);
                }
                lacc = __builtin_amdgcn_mfma_f32_16x16x32_bf16(pf, ones, lacc, 0, 0, 0);
            }
#pragma unroll
            for (int r = 0; r < 4; r++)
                l_i[r] = l_i[r] * alr[r] + lacc[r];
        }

        // epilogue: out[b*T + t, h*128 + d] = o/l  (overwrites this block's own q — safe)
#pragma unroll
        for (int r = 0; r < 4; r++) {
            const float inv = 1.0f / fmaxf(l_i[r], 1e-20f);
            const int trow = qrow0 + quad * 4 + r;
#pragma unroll
            for (int jd = 0; jd < 8; jd++) {
                const int col = h * HDn + jd * 16 + l15;
                outp[(size_t)(b * Tn + trow) * Cn + col] = f2b(o_acc[jd][r] * inv);
            }
        }
    }
}

extern "C" void kernel_launch(void* const* d_in, const int* in_sizes, int n_in,
                              void* d_out, int out_size, void* d_ws, size_t ws_size,
                              hipStream_t stream)
{
    const float* x      = (const float*)d_in[0]; // [B,T,C]  fp32
    const float* w_attn = (const float*)d_in[1]; // [3C,C]   fp32
    const float* w_proj = (const float*)d_in[2]; // [C,C]    fp32
    const float* b_proj = (const float*)d_in[3]; // [C]      fp32
    float* out = (float*)d_out;                  // [B,T,C]  fp32 (32 MiB)

    const size_t MiB = 1024 * 1024;
    unsigned short* kvbuf = (unsigned short*)d_out;   // [4096,4096] bf16 scratch in d_out

    const int nx   = Bn * Tn * Cn;         // 8.4M
    const int nwq  = Cn * Cn;              // 4.2M
    const int nwkv = 2 * Cn * Cn;          // 8.4M

    if (ws_size >= 56 * MiB) {
        // FUSED PATH: xb [0,16M) | qbuf [16M,32M) | wb [32M,56M) holds full w_attn bf16
        unsigned short* xb   = (unsigned short*)d_ws;
        unsigned short* qbuf = (unsigned short*)((char*)d_ws + 16 * MiB);
        unsigned short* wb   = (unsigned short*)((char*)d_ws + 32 * MiB);
        const int nwa = 3 * Cn * Cn;       // 12.6M

        cvt_kernel<<<nx / 8 / 256, 256, 0, stream>>>(x, xb, nx);
        cvt_kernel<<<nwa / 8 / 256, 256, 0, stream>>>(w_attn, wb, nwa);
        gemm_qkv192_kernel<<<dim3(512), 512, 0, stream>>>(xb, wb, qbuf, kvbuf);
        attn_kernel<<<dim3(8, Bn * Hn), 512, 0, stream>>>(qbuf, kvbuf, qbuf);
        cvt_kernel<<<nwq / 8 / 256, 256, 0, stream>>>(w_proj, wb, nwq);
        gemm_bb_kernel<1, 1><<<dim3(32, 16), 256, 0, stream>>>(qbuf, wb, b_proj, out,
                                                               Bn * Tn, Cn, Cn);
    } else {
        // 48-MiB PATH (rounds 5-6 proven): xb | qbuf | wb(16M, chunked weights)
        unsigned short* xb   = (unsigned short*)d_ws;
        unsigned short* qbuf = (unsigned short*)((char*)d_ws + 16 * MiB);
        unsigned short* wb   = (unsigned short*)((char*)d_ws + 32 * MiB);

        cvt_kernel<<<nx / 8 / 256, 256, 0, stream>>>(x, xb, nx);
        cvt_kernel<<<nwq / 8 / 256, 256, 0, stream>>>(w_attn, wb, nwq);
        gemm_bb_kernel<0, 0><<<dim3(32, 16), 256, 0, stream>>>(xb, wb, nullptr, qbuf,
                                                               Bn * Tn, Cn, Cn);
        cvt_kernel<<<nwkv / 8 / 256, 256, 0, stream>>>(w_attn + (size_t)Cn * Cn, wb, nwkv);
        gemm_bb_kernel<0, 0><<<dim3(32, 32), 256, 0, stream>>>(xb, wb, nullptr, kvbuf,
                                                               Bn * Tn, 2 * Cn, Cn);
        attn_kernel<<<dim3(8, Bn * Hn), 512, 0, stream>>>(qbuf, kvbuf, qbuf);
        cvt_kernel<<<nwq / 8 / 256, 256, 0, stream>>>(w_proj, wb, nwq);
        gemm_bb_kernel<1, 1><<<dim3(32, 16), 256, 0, stream>>>(qbuf, wb, b_proj, out,
                                                               Bn * Tn, Cn, Cn);
    }
}